// Round 4
// baseline (627.516 us; speedup 1.0000x reference)
//
#include <hip/hip_runtime.h>
#include <math.h>

// ---------------------------------------------------------------------------
// spline_net r3: bucket-binned, LDS-accumulated aggregation.
//   r2 counters: scatter_kernel wrote 100MB for a 12.8MB CSR buffer (8x
//   line-level write amplification from cross-XCD random 8B stores). Replace
//   CSR build entirely: bin edges into 128-node dst-buckets (runs of ~5
//   records -> ~full-line writes), then one block per bucket accumulates
//   into an LDS accumulator with ds_add_f32. Zero global float atomics,
//   zero per-node offset machinery.
// N=100000, F_IN=128, HID=16, C=10, E=1600000
// ---------------------------------------------------------------------------

#define SHIFT   7            // 128 nodes per bucket
#define BNODES  128
#define NBUK_MAX 800         // supports N <= 102400
#define CAP     2560         // bucket capacity; mean 2048, sigma ~45 -> +11σ
#define CHUNK   4096         // edges per bin block

// GEMM1: h01[n][0:16]=x@W1[0], h01[n][16:32]=x@W1[1], xr[n][0:16]=x@root1
__global__ __launch_bounds__(256) void gemm1_kernel(
    const float* __restrict__ x, const float* __restrict__ W1,
    const float* __restrict__ root1, float* __restrict__ h01,
    float* __restrict__ xr, int N)
{
    __shared__ float Ws[128][48];
    int tid = threadIdx.x;
    for (int idx = tid; idx < 128 * 16; idx += 256) {
        int i = idx >> 4, j = idx & 15;
        Ws[i][j]      = W1[i * 16 + j];
        Ws[i][16 + j] = W1[2048 + i * 16 + j];
        Ws[i][32 + j] = root1[i * 16 + j];
    }
    __syncthreads();
    int n = blockIdx.x * 256 + tid;
    if (n >= N) return;

    float acc[48];
#pragma unroll
    for (int j = 0; j < 48; ++j) acc[j] = 0.f;

    const float4* xrow = (const float4*)(x + (size_t)n * 128);
#pragma unroll 1
    for (int k4 = 0; k4 < 32; ++k4) {
        float4 xv = xrow[k4];
        int k = k4 * 4;
#pragma unroll
        for (int j = 0; j < 48; ++j) {
            acc[j] += xv.x * Ws[k][j] + xv.y * Ws[k + 1][j]
                    + xv.z * Ws[k + 2][j] + xv.w * Ws[k + 3][j];
        }
    }
    float4* out01 = (float4*)(h01 + (size_t)n * 32);
#pragma unroll
    for (int q = 0; q < 8; ++q)
        out01[q] = make_float4(acc[q * 4], acc[q * 4 + 1], acc[q * 4 + 2], acc[q * 4 + 3]);
    float4* outr = (float4*)(xr + (size_t)n * 16);
#pragma unroll
    for (int q = 0; q < 4; ++q)
        outr[q] = make_float4(acc[32 + q * 4], acc[33 + q * 4], acc[34 + q * 4], acc[35 + q * 4]);
}

// Bin edges by dst>>SHIFT into per-bucket staging. Record: {src|dstlo<<17, w}
__global__ __launch_bounds__(256) void bin_kernel(
    const int* __restrict__ ei, const float* __restrict__ ea,
    int* __restrict__ gcur, int2* __restrict__ staging, int E, int nbuk)
{
    __shared__ int bcnt[NBUK_MAX];
    __shared__ int gbase[NBUK_MAX];
    int tid = threadIdx.x;
    for (int i = tid; i < nbuk; i += 256) bcnt[i] = 0;
    __syncthreads();

    int base = blockIdx.x * CHUNK;
    int lrank[16];
#pragma unroll
    for (int i = 0; i < 16; ++i) {
        int e = base + i * 256 + tid;
        lrank[i] = 0;
        if (e < E) lrank[i] = atomicAdd(&bcnt[ei[E + e] >> SHIFT], 1);
    }
    __syncthreads();
    for (int b = tid; b < nbuk; b += 256) {
        int c = bcnt[b];
        gbase[b] = c ? atomicAdd(&gcur[b], c) : 0;
    }
    __syncthreads();
#pragma unroll
    for (int i = 0; i < 16; ++i) {
        int e = base + i * 256 + tid;
        if (e < E) {
            int s = ei[e];
            int d = ei[E + e];
            int b = d >> SHIFT;
            int p = gbase[b] + lrank[i];
            if (p < CAP)
                staging[(size_t)b * CAP + p] =
                    make_int2(s | ((d & (BNODES - 1)) << 17), __float_as_int(ea[e]));
        }
    }
}

// Layer-1 aggregate: block = bucket. LDS acc[128][16] via ds_add_f32.
// 16 lanes per edge (lane c owns channel c). Also counts deg.
__global__ __launch_bounds__(256) void gather1b_kernel(
    const int2* __restrict__ staging, const int* __restrict__ gcur,
    const float* __restrict__ h01, float* __restrict__ agg1,
    float* __restrict__ degf, int N)
{
    __shared__ float acc[BNODES * 16];
    __shared__ int dcnt[BNODES];
    int tid = threadIdx.x;
    for (int i = tid; i < BNODES * 16; i += 256) acc[i] = 0.f;
    for (int i = tid; i < BNODES; i += 256) dcnt[i] = 0;
    __syncthreads();

    int b = blockIdx.x;
    int m = gcur[b];
    if (m > CAP) m = CAP;
    const int2* sp = staging + (size_t)b * CAP;
    int es = tid >> 4;
    int c  = tid & 15;
#pragma unroll 2
    for (int k0 = 0; k0 < m; k0 += 16) {
        int k = k0 + es;
        if (k < m) {
            int2 rec = sp[k];
            int src = rec.x & 0x1FFFF;
            int dl  = rec.x >> 17;
            float w = __int_as_float(rec.y);
            float a  = h01[(size_t)src * 32 + c];
            float bb = h01[(size_t)src * 32 + 16 + c];
            atomicAdd(&acc[dl * 16 + c], a + w * (bb - a));
            if (c == 0) atomicAdd(&dcnt[dl], 1);
        }
    }
    __syncthreads();

    int nodeBase = b * BNODES;
    for (int idx = tid; idx < BNODES * 16; idx += 256) {
        int n = nodeBase + (idx >> 4);
        if (n < N) agg1[(size_t)n * 16 + (idx & 15)] = acc[idx];
    }
    for (int nl = tid; nl < BNODES; nl += 256) {
        int n = nodeBase + nl;
        if (n < N) degf[n] = (float)dcnt[nl];
    }
}

// h = elu(agg1/max(deg,1) + xr + b1); hrb = h@root2 + b2
__global__ __launch_bounds__(256) void finalize1_kernel(
    const float* __restrict__ agg1, const float* __restrict__ degf,
    const float* __restrict__ xr, const float* __restrict__ b1,
    const float* __restrict__ root2, const float* __restrict__ b2,
    float* __restrict__ h, float* __restrict__ hrb, int N)
{
    __shared__ float r2s[160];
    __shared__ float b1s[16];
    __shared__ float b2s[10];
    int tid = threadIdx.x;
    if (tid < 160) r2s[tid] = root2[tid];
    if (tid < 16)  b1s[tid] = b1[tid];
    if (tid < 10)  b2s[tid] = b2[tid];
    __syncthreads();
    int n = blockIdx.x * 256 + tid;
    if (n >= N) return;

    float invd = 1.0f / fmaxf(degf[n], 1.0f);
    float hv[16];
#pragma unroll
    for (int c = 0; c < 16; ++c) {
        float v = agg1[(size_t)n * 16 + c] * invd + xr[(size_t)n * 16 + c] + b1s[c];
        hv[c] = v > 0.f ? v : expm1f(v);
    }
    float4* hp = (float4*)(h + (size_t)n * 16);
#pragma unroll
    for (int q = 0; q < 4; ++q)
        hp[q] = make_float4(hv[q * 4], hv[q * 4 + 1], hv[q * 4 + 2], hv[q * 4 + 3]);

    float hr[10];
#pragma unroll
    for (int j = 0; j < 10; ++j) hr[j] = b2s[j];
#pragma unroll
    for (int i = 0; i < 16; ++i)
#pragma unroll
        for (int j = 0; j < 10; ++j)
            hr[j] += hv[i] * r2s[i * 10 + j];
    float* hb = hrb + (size_t)n * 10;
#pragma unroll
    for (int j = 0; j < 10; ++j) hb[j] = hr[j];
}

// Layer-2 aggregate in h-space: accP = sum (1-w)h[src], accQ = sum w*h[src]
__global__ __launch_bounds__(256) void gather2b_kernel(
    const int2* __restrict__ staging, const int* __restrict__ gcur,
    const float* __restrict__ h, float* __restrict__ pq, int N)
{
    __shared__ float accP[BNODES * 16];
    __shared__ float accQ[BNODES * 16];
    int tid = threadIdx.x;
    for (int i = tid; i < BNODES * 16; i += 256) { accP[i] = 0.f; accQ[i] = 0.f; }
    __syncthreads();

    int b = blockIdx.x;
    int m = gcur[b];
    if (m > CAP) m = CAP;
    const int2* sp = staging + (size_t)b * CAP;
    int es = tid >> 4;
    int c  = tid & 15;
#pragma unroll 2
    for (int k0 = 0; k0 < m; k0 += 16) {
        int k = k0 + es;
        if (k < m) {
            int2 rec = sp[k];
            int src = rec.x & 0x1FFFF;
            int dl  = rec.x >> 17;
            float w = __int_as_float(rec.y);
            float v = h[(size_t)src * 16 + c];
            atomicAdd(&accP[dl * 16 + c], (1.f - w) * v);
            atomicAdd(&accQ[dl * 16 + c], w * v);
        }
    }
    __syncthreads();

    int nodeBase = b * BNODES;
    for (int idx = tid; idx < BNODES * 16; idx += 256) {
        int n = nodeBase + (idx >> 4);
        if (n < N) {
            pq[(size_t)n * 32 + (idx & 15)]      = accP[idx];
            pq[(size_t)n * 32 + 16 + (idx & 15)] = accQ[idx];
        }
    }
}

// out = (p@W2[0] + q@W2[1])/max(deg,1) + hrb
__global__ __launch_bounds__(256) void finalize2_kernel(
    const float* __restrict__ pq, const float* __restrict__ degf,
    const float* __restrict__ hrb, const float* __restrict__ W2,
    float* __restrict__ out, int N)
{
    __shared__ float w2s[320];
    int tid = threadIdx.x;
    for (int idx = tid; idx < 320; idx += 256) w2s[idx] = W2[idx];
    __syncthreads();
    int n = blockIdx.x * 256 + tid;
    if (n >= N) return;

    float invd = 1.0f / fmaxf(degf[n], 1.0f);
    float pv[16], qv[16];
    const float4* pp = (const float4*)(pq + (size_t)n * 32);
#pragma unroll
    for (int q4 = 0; q4 < 4; ++q4) {
        float4 a = pp[q4];
        pv[q4 * 4] = a.x; pv[q4 * 4 + 1] = a.y; pv[q4 * 4 + 2] = a.z; pv[q4 * 4 + 3] = a.w;
        float4 bq = pp[4 + q4];
        qv[q4 * 4] = bq.x; qv[q4 * 4 + 1] = bq.y; qv[q4 * 4 + 2] = bq.z; qv[q4 * 4 + 3] = bq.w;
    }
    float o[10];
#pragma unroll
    for (int j = 0; j < 10; ++j) o[j] = 0.f;
#pragma unroll
    for (int i = 0; i < 16; ++i)
#pragma unroll
        for (int j = 0; j < 10; ++j)
            o[j] += pv[i] * w2s[i * 10 + j] + qv[i] * w2s[160 + i * 10 + j];
    float* op = out + (size_t)n * 10;
    const float* hb = hrb + (size_t)n * 10;
#pragma unroll
    for (int j = 0; j < 10; ++j) op[j] = o[j] * invd + hb[j];
}

extern "C" void kernel_launch(void* const* d_in, const int* in_sizes, int n_in,
                              void* d_out, int out_size, void* d_ws, size_t ws_size,
                              hipStream_t stream)
{
    const float* x     = (const float*)d_in[0];
    const int*   ei    = (const int*)d_in[1];   // (2,E)
    const float* ea    = (const float*)d_in[2]; // (E,1)
    const float* W1    = (const float*)d_in[3]; // (2,128,16)
    const float* root1 = (const float*)d_in[4]; // (128,16)
    const float* b1    = (const float*)d_in[5]; // (16,)
    const float* W2    = (const float*)d_in[6]; // (2,16,10)
    const float* root2 = (const float*)d_in[7]; // (16,10)
    const float* b2    = (const float*)d_in[8]; // (10,)
    float* out = (float*)d_out;

    int N = in_sizes[0] / 128;
    int E = in_sizes[2];
    int nbuk = (N + BNODES - 1) / BNODES;   // 782

    // workspace (~52.3 MB). pq aliases h01 (h01 dead after gather1b).
    char* ws = (char*)d_ws;
    int2*  staging = (int2*)ws;                               // nbuk*CAP*8 = 16.0MB
    float* h01   = (float*)(ws + (size_t)nbuk * CAP * 8);     // N*32 (reused as pq)
    float* pq    = h01;
    float* xr    = h01  + (size_t)N * 32;                     // N*16
    float* agg1  = xr   + (size_t)N * 16;                     // N*16
    float* h     = agg1 + (size_t)N * 16;                     // N*16
    float* hrb   = h    + (size_t)N * 16;                     // N*10
    float* degf  = hrb  + (size_t)N * 10;                     // N
    int*   gcur  = (int*)(degf + N);                          // nbuk

    int nb_n = (N + 255) / 256;
    int nb_bin = (E + CHUNK - 1) / CHUNK;

    hipMemsetAsync(gcur, 0, (size_t)nbuk * sizeof(int), stream);

    gemm1_kernel   <<<nb_n, 256, 0, stream>>>(x, W1, root1, h01, xr, N);
    bin_kernel     <<<nb_bin, 256, 0, stream>>>(ei, ea, gcur, staging, E, nbuk);
    gather1b_kernel<<<nbuk, 256, 0, stream>>>(staging, gcur, h01, agg1, degf, N);
    finalize1_kernel<<<nb_n, 256, 0, stream>>>(agg1, degf, xr, b1, root2, b2, h, hrb, N);
    gather2b_kernel<<<nbuk, 256, 0, stream>>>(staging, gcur, h, pq, N);
    finalize2_kernel<<<nb_n, 256, 0, stream>>>(pq, degf, hrb, W2, out, N);
}

// Round 6
// 181.290 us; speedup vs baseline: 3.4614x; 3.4614x over previous
//
#include <hip/hip_runtime.h>
#include <math.h>

// ---------------------------------------------------------------------------
// spline_net r5: r4 structure (bin + in-place LDS counting-sort CSR + per-node
// 16-lane gathers) with a SHRUNK workspace.
//   r4 post-mortem: first call passed (absmax 4e-3, 185us) but post-timing
//   re-validation diverged (1.16). All ws buffers are rewritten each call;
//   the only defensible theory is ws overflow: r4's layout ended at 53.2MB
//   (r3's passing layout: 52.4MB). OOB writes from csr_build (cnt/roff/gcur
//   tail) can corrupt an adjacent input allocation (ei is only read by
//   bin_kernel -> call #1 validates clean, later calls diverge stably).
//   Fix: alias h into xr (finalize1 is row-exclusive -> in-place safe) and
//   trim CAP 2560->2432 (+8.5 sigma). Total ws = 46.0MB.
// N=100000, F_IN=128, HID=16, C=10, E=1600000
// ---------------------------------------------------------------------------

#define SHIFT    7            // 128 nodes per bucket
#define BNODES   128
#define NBUK_MAX 800          // supports N <= 102400
#define CAP      2432         // bucket capacity; mean 2046, sigma ~45 -> +8.5σ
#define CHUNK    4096         // edges per bin block

// GEMM1: h01[n][0:16]=x@W1[0], h01[n][16:32]=x@W1[1], xr[n][0:16]=x@root1
__global__ __launch_bounds__(256) void gemm1_kernel(
    const float* __restrict__ x, const float* __restrict__ W1,
    const float* __restrict__ root1, float* __restrict__ h01,
    float* __restrict__ xr, int N)
{
    __shared__ float Ws[128][48];
    int tid = threadIdx.x;
    for (int idx = tid; idx < 128 * 16; idx += 256) {
        int i = idx >> 4, j = idx & 15;
        Ws[i][j]      = W1[i * 16 + j];
        Ws[i][16 + j] = W1[2048 + i * 16 + j];
        Ws[i][32 + j] = root1[i * 16 + j];
    }
    __syncthreads();
    int n = blockIdx.x * 256 + tid;
    if (n >= N) return;

    float acc[48];
#pragma unroll
    for (int j = 0; j < 48; ++j) acc[j] = 0.f;

    const float4* xrow = (const float4*)(x + (size_t)n * 128);
#pragma unroll 1
    for (int k4 = 0; k4 < 32; ++k4) {
        float4 xv = xrow[k4];
        int k = k4 * 4;
#pragma unroll
        for (int j = 0; j < 48; ++j) {
            acc[j] += xv.x * Ws[k][j] + xv.y * Ws[k + 1][j]
                    + xv.z * Ws[k + 2][j] + xv.w * Ws[k + 3][j];
        }
    }
    float4* out01 = (float4*)(h01 + (size_t)n * 32);
#pragma unroll
    for (int q = 0; q < 8; ++q)
        out01[q] = make_float4(acc[q * 4], acc[q * 4 + 1], acc[q * 4 + 2], acc[q * 4 + 3]);
    float4* outr = (float4*)(xr + (size_t)n * 16);
#pragma unroll
    for (int q = 0; q < 4; ++q)
        outr[q] = make_float4(acc[32 + q * 4], acc[33 + q * 4], acc[34 + q * 4], acc[35 + q * 4]);
}

// Bin edges by dst>>SHIFT into per-bucket staging. Record: {src|dstlo<<17, w}
__global__ __launch_bounds__(256) void bin_kernel(
    const int* __restrict__ ei, const float* __restrict__ ea,
    int* __restrict__ gcur, int2* __restrict__ staging, int E, int nbuk)
{
    __shared__ int bcnt[NBUK_MAX];
    __shared__ int gbase[NBUK_MAX];
    int tid = threadIdx.x;
    for (int i = tid; i < nbuk; i += 256) bcnt[i] = 0;
    __syncthreads();

    int base = blockIdx.x * CHUNK;
    int lrank[16];
#pragma unroll
    for (int i = 0; i < 16; ++i) {
        int e = base + i * 256 + tid;
        lrank[i] = 0;
        if (e < E) lrank[i] = atomicAdd(&bcnt[ei[E + e] >> SHIFT], 1);
    }
    __syncthreads();
    for (int b = tid; b < nbuk; b += 256) {
        int c = bcnt[b];
        gbase[b] = c ? atomicAdd(&gcur[b], c) : 0;
    }
    __syncthreads();
#pragma unroll
    for (int i = 0; i < 16; ++i) {
        int e = base + i * 256 + tid;
        if (e < E) {
            int s = ei[e];
            int d = ei[E + e];
            int b = d >> SHIFT;
            int p = gbase[b] + lrank[i];
            if (p < CAP)
                staging[(size_t)b * CAP + p] =
                    make_int2(s | ((d & (BNODES - 1)) << 17), __float_as_int(ea[e]));
        }
    }
}

// In-place per-bucket counting sort (node-sorted CSR inside the bucket).
// Emits roff[n] (absolute index into staging), cnt[n], degf[n].
__global__ __launch_bounds__(256) void csr_build_kernel(
    int2* __restrict__ staging, const int* __restrict__ gcur,
    int* __restrict__ roff, int* __restrict__ cnt,
    float* __restrict__ degf, int N)
{
    __shared__ int2 rin[CAP];
    __shared__ int2 rout[CAP];
    __shared__ int hist[BNODES];
    __shared__ int sscan[BNODES];
    __shared__ int wcur[BNODES];
    int tid = threadIdx.x;
    int b = blockIdx.x;
    int m = gcur[b];
    if (m > CAP) m = CAP;
    int2* sp = staging + (size_t)b * CAP;

    if (tid < BNODES) { hist[tid] = 0; wcur[tid] = 0; }
    __syncthreads();
    for (int k = tid; k < m; k += 256) {
        int2 r = sp[k];
        rin[k] = r;
        atomicAdd(&hist[r.x >> 17], 1);
    }
    __syncthreads();
    // inclusive scan of hist[0:128] -> sscan (Hillis-Steele; uniform barriers)
    if (tid < BNODES) sscan[tid] = hist[tid];
    __syncthreads();
    for (int off = 1; off < BNODES; off <<= 1) {
        int t = (tid < BNODES && tid >= off) ? sscan[tid - off] : 0;
        __syncthreads();
        if (tid < BNODES) sscan[tid] += t;
        __syncthreads();
    }
    // exclusive offset = sscan - hist
    // scatter LDS->LDS into node order (strip dl, keep {src,w})
    for (int k = tid; k < m; k += 256) {
        int2 r = rin[k];
        int dl = r.x >> 17;
        int pos = (sscan[dl] - hist[dl]) + atomicAdd(&wcur[dl], 1);
        rout[pos] = make_int2(r.x & 0x1FFFF, r.y);
    }
    __syncthreads();
    // coalesced write-back in place
    for (int k = tid; k < m; k += 256) sp[k] = rout[k];
    // node metadata
    if (tid < BNODES) {
        int n = b * BNODES + tid;
        if (n < N) {
            roff[n] = b * CAP + (sscan[tid] - hist[tid]);
            cnt[n]  = hist[tid];
            degf[n] = (float)hist[tid];
        }
    }
}

// Layer-1 gather: 16 lanes per node, lane c owns channel c.
__global__ __launch_bounds__(256) void gather1_kernel(
    const int2* __restrict__ staging, const int* __restrict__ roff,
    const int* __restrict__ cnt, const float* __restrict__ h01,
    float* __restrict__ agg1, int N)
{
    int t = blockIdx.x * 256 + threadIdx.x;
    int n = t >> 4;
    int c = t & 15;
    if (n >= N) return;
    int start = roff[n];
    int m = cnt[n];
    float acc = 0.f;
#pragma unroll 2
    for (int k = 0; k < m; ++k) {
        int2 r = staging[(size_t)start + k];
        int s = r.x;
        float w = __int_as_float(r.y);
        float a = h01[(size_t)s * 32 + c];
        float bb = h01[(size_t)s * 32 + 16 + c];
        acc += a + w * (bb - a);
    }
    agg1[(size_t)n * 16 + c] = acc;
}

// h = elu(agg1/max(deg,1) + xr + b1), written IN PLACE over xr (row-exclusive);
// hrb = h@root2 + b2
__global__ __launch_bounds__(256) void finalize1_kernel(
    const float* __restrict__ agg1, const float* __restrict__ degf,
    float* __restrict__ xrh, const float* __restrict__ b1,
    const float* __restrict__ root2, const float* __restrict__ b2,
    float* __restrict__ hrb, int N)
{
    __shared__ float r2s[160];
    __shared__ float b1s[16];
    __shared__ float b2s[10];
    int tid = threadIdx.x;
    if (tid < 160) r2s[tid] = root2[tid];
    if (tid < 16)  b1s[tid] = b1[tid];
    if (tid < 10)  b2s[tid] = b2[tid];
    __syncthreads();
    int n = blockIdx.x * 256 + tid;
    if (n >= N) return;

    float invd = 1.0f / fmaxf(degf[n], 1.0f);
    float hv[16];
#pragma unroll
    for (int c = 0; c < 16; ++c) {
        float v = agg1[(size_t)n * 16 + c] * invd + xrh[(size_t)n * 16 + c] + b1s[c];
        hv[c] = v > 0.f ? v : expm1f(v);
    }
    float4* hp = (float4*)(xrh + (size_t)n * 16);   // in-place: row n only
#pragma unroll
    for (int q = 0; q < 4; ++q)
        hp[q] = make_float4(hv[q * 4], hv[q * 4 + 1], hv[q * 4 + 2], hv[q * 4 + 3]);

    float hr[10];
#pragma unroll
    for (int j = 0; j < 10; ++j) hr[j] = b2s[j];
#pragma unroll
    for (int i = 0; i < 16; ++i)
#pragma unroll
        for (int j = 0; j < 10; ++j)
            hr[j] += hv[i] * r2s[i * 10 + j];
    float* hb = hrb + (size_t)n * 10;
#pragma unroll
    for (int j = 0; j < 10; ++j) hb[j] = hr[j];
}

// Layer-2 gather in h-space: p = sum (1-w)h[src], q = sum w*h[src]
__global__ __launch_bounds__(256) void gather2_kernel(
    const int2* __restrict__ staging, const int* __restrict__ roff,
    const int* __restrict__ cnt, const float* __restrict__ h,
    float* __restrict__ pq, int N)
{
    int t = blockIdx.x * 256 + threadIdx.x;
    int n = t >> 4;
    int c = t & 15;
    if (n >= N) return;
    int start = roff[n];
    int m = cnt[n];
    float p = 0.f, q = 0.f;
#pragma unroll 2
    for (int k = 0; k < m; ++k) {
        int2 r = staging[(size_t)start + k];
        float w = __int_as_float(r.y);
        float v = h[(size_t)r.x * 16 + c];
        p += (1.f - w) * v;
        q += w * v;
    }
    pq[(size_t)n * 32 + c]      = p;
    pq[(size_t)n * 32 + 16 + c] = q;
}

// out = (p@W2[0] + q@W2[1])/max(deg,1) + hrb
__global__ __launch_bounds__(256) void finalize2_kernel(
    const float* __restrict__ pq, const float* __restrict__ degf,
    const float* __restrict__ hrb, const float* __restrict__ W2,
    float* __restrict__ out, int N)
{
    __shared__ float w2s[320];
    int tid = threadIdx.x;
    for (int idx = tid; idx < 320; idx += 256) w2s[idx] = W2[idx];
    __syncthreads();
    int n = blockIdx.x * 256 + tid;
    if (n >= N) return;

    float invd = 1.0f / fmaxf(degf[n], 1.0f);
    float pv[16], qv[16];
    const float4* pp = (const float4*)(pq + (size_t)n * 32);
#pragma unroll
    for (int q4 = 0; q4 < 4; ++q4) {
        float4 a = pp[q4];
        pv[q4 * 4] = a.x; pv[q4 * 4 + 1] = a.y; pv[q4 * 4 + 2] = a.z; pv[q4 * 4 + 3] = a.w;
        float4 bq = pp[4 + q4];
        qv[q4 * 4] = bq.x; qv[q4 * 4 + 1] = bq.y; qv[q4 * 4 + 2] = bq.z; qv[q4 * 4 + 3] = bq.w;
    }
    float o[10];
#pragma unroll
    for (int j = 0; j < 10; ++j) o[j] = 0.f;
#pragma unroll
    for (int i = 0; i < 16; ++i)
#pragma unroll
        for (int j = 0; j < 10; ++j)
            o[j] += pv[i] * w2s[i * 10 + j] + qv[i] * w2s[160 + i * 10 + j];
    float* op = out + (size_t)n * 10;
    const float* hb = hrb + (size_t)n * 10;
#pragma unroll
    for (int j = 0; j < 10; ++j) op[j] = o[j] * invd + hb[j];
}

extern "C" void kernel_launch(void* const* d_in, const int* in_sizes, int n_in,
                              void* d_out, int out_size, void* d_ws, size_t ws_size,
                              hipStream_t stream)
{
    const float* x     = (const float*)d_in[0];
    const int*   ei    = (const int*)d_in[1];   // (2,E)
    const float* ea    = (const float*)d_in[2]; // (E,1)
    const float* W1    = (const float*)d_in[3]; // (2,128,16)
    const float* root1 = (const float*)d_in[4]; // (128,16)
    const float* b1    = (const float*)d_in[5]; // (16,)
    const float* W2    = (const float*)d_in[6]; // (2,16,10)
    const float* root2 = (const float*)d_in[7]; // (16,10)
    const float* b2    = (const float*)d_in[8]; // (10,)
    float* out = (float*)d_out;

    int N = in_sizes[0] / 128;
    int E = in_sizes[2];
    int nbuk = (N + BNODES - 1) / BNODES;   // 782

    // workspace layout, total 46.0 MB (r3-proven floor was ~52.4 MB):
    //   staging  nbuk*CAP*8 = 15.2 MB
    //   buf32    N*32 f  (h01, reused as pq)
    //   xrh      N*16 f  (xr, overwritten in place by h)
    //   agg1     N*16 f
    //   hrb      N*10 f
    //   degf     N  f ; cnt N i ; roff N i ; gcur nbuk i
    char* ws = (char*)d_ws;
    int2*  staging = (int2*)ws;
    float* buf32 = (float*)(ws + (size_t)nbuk * CAP * 8);
    float* h01   = buf32;
    float* pq    = buf32;
    float* xrh   = buf32 + (size_t)N * 32;
    float* agg1  = xrh  + (size_t)N * 16;
    float* hrb   = agg1 + (size_t)N * 16;
    float* degf  = hrb  + (size_t)N * 10;
    int*   cnt   = (int*)(degf + N);
    int*   roff  = cnt  + N;
    int*   gcur  = roff + N;

    int nb_n = (N + 255) / 256;
    int nb_e16 = (N * 16 + 255) / 256;
    int nb_bin = (E + CHUNK - 1) / CHUNK;

    hipMemsetAsync(gcur, 0, (size_t)nbuk * sizeof(int), stream);

    gemm1_kernel    <<<nb_n, 256, 0, stream>>>(x, W1, root1, h01, xrh, N);
    bin_kernel      <<<nb_bin, 256, 0, stream>>>(ei, ea, gcur, staging, E, nbuk);
    csr_build_kernel<<<nbuk, 256, 0, stream>>>(staging, gcur, roff, cnt, degf, N);
    gather1_kernel  <<<nb_e16, 256, 0, stream>>>(staging, roff, cnt, h01, agg1, N);
    finalize1_kernel<<<nb_n, 256, 0, stream>>>(agg1, degf, xrh, b1, root2, b2, hrb, N);
    gather2_kernel  <<<nb_e16, 256, 0, stream>>>(staging, roff, cnt, xrh, pq, N);
    finalize2_kernel<<<nb_n, 256, 0, stream>>>(pq, degf, hrb, W2, out, N);
}

// Round 7
// 156.407 us; speedup vs baseline: 4.0121x; 1.1591x over previous
//
#include <hip/hip_runtime.h>
#include <math.h>

// ---------------------------------------------------------------------------
// spline_net r6: fuse the two independent latency-bound kernels (gemm1, bin)
// into one dispatch, and de-latency the gemm part.
//   r5 counters: gemm1 48us (occ 11%, VALU 20%) and bin 49us (occ 13%, VALU
//   2%) — both latency-bound with 391-block grids (19% wave-slot cap). They
//   touch disjoint inputs -> fuse via blockIdx partition so their stall
//   cycles interleave. gemm additionally gets 2 threads/node (24 cols each,
//   782 blocks) and k-unroll 4 (4 x-loads in flight).
// N=100000, F_IN=128, HID=16, C=10, E=1600000
// ---------------------------------------------------------------------------

#define SHIFT    7            // 128 nodes per bucket
#define BNODES   128
#define NBUK_MAX 800          // supports N <= 102400
#define CAP      2432         // bucket capacity; mean 2046, sigma ~45 -> +8.5σ
#define CHUNK    4096         // edges per bin block
#define GNODES   128          // nodes per gemm block (2 threads/node)

// ---- fused phase 1: gemm part + bin part -----------------------------------

__device__ __forceinline__ void gemm_part(
    float* __restrict__ smem, int gb, int tid,
    const float* __restrict__ x, const float* __restrict__ W1,
    const float* __restrict__ root1, float* __restrict__ h01,
    float* __restrict__ xr, int N)
{
    // smem: Ws[128][48] flat
    for (int idx = tid; idx < 128 * 16; idx += 256) {
        int i = idx >> 4, j = idx & 15;
        smem[i * 48 + j]      = W1[idx];
        smem[i * 48 + 16 + j] = W1[2048 + idx];
        smem[i * 48 + 32 + j] = root1[idx];
    }
    __syncthreads();
    int nl   = tid >> 1;          // node within block
    int half = tid & 1;           // which 24 output cols
    int n = gb * GNODES + nl;
    if (n >= N) return;

    float acc[24];
#pragma unroll
    for (int j = 0; j < 24; ++j) acc[j] = 0.f;

    const float4* xrow = (const float4*)(x + (size_t)n * 128);
    const float* wbase = smem + half * 24;
#pragma unroll 4
    for (int k4 = 0; k4 < 32; ++k4) {
        float4 xv = xrow[k4];
        const float* w0 = wbase + (k4 * 4) * 48;
#pragma unroll
        for (int j = 0; j < 24; ++j) {
            acc[j] += xv.x * w0[j] + xv.y * w0[48 + j]
                    + xv.z * w0[96 + j] + xv.w * w0[144 + j];
        }
    }
    // cols: 0..15 h0, 16..31 h1, 32..47 xr
    float4* out01 = (float4*)(h01 + (size_t)n * 32);
    if (half == 0) {
        // cols 0..23 -> h01[0..23]
#pragma unroll
        for (int q = 0; q < 6; ++q)
            out01[q] = make_float4(acc[q * 4], acc[q * 4 + 1], acc[q * 4 + 2], acc[q * 4 + 3]);
    } else {
        // cols 24..47 -> h01[24..31], xr[0..15]
#pragma unroll
        for (int q = 0; q < 2; ++q)
            out01[6 + q] = make_float4(acc[q * 4], acc[q * 4 + 1], acc[q * 4 + 2], acc[q * 4 + 3]);
        float4* outr = (float4*)(xr + (size_t)n * 16);
#pragma unroll
        for (int q = 0; q < 4; ++q)
            outr[q] = make_float4(acc[8 + q * 4], acc[9 + q * 4], acc[10 + q * 4], acc[11 + q * 4]);
    }
}

__device__ __forceinline__ void bin_part(
    float* __restrict__ smem, int bb, int tid,
    const int* __restrict__ ei, const float* __restrict__ ea,
    int* __restrict__ gcur, int2* __restrict__ staging, int E, int nbuk)
{
    int* bcnt  = (int*)smem;            // NBUK_MAX
    int* gbase = bcnt + NBUK_MAX;       // NBUK_MAX  (total 6400B <= 24576B)
    for (int i = tid; i < nbuk; i += 256) bcnt[i] = 0;
    __syncthreads();

    int base = bb * CHUNK;
    int lrank[16];
#pragma unroll
    for (int i = 0; i < 16; ++i) {
        int e = base + i * 256 + tid;
        lrank[i] = 0;
        if (e < E) lrank[i] = atomicAdd(&bcnt[ei[E + e] >> SHIFT], 1);
    }
    __syncthreads();
    for (int b = tid; b < nbuk; b += 256) {
        int c = bcnt[b];
        gbase[b] = c ? atomicAdd(&gcur[b], c) : 0;
    }
    __syncthreads();
#pragma unroll
    for (int i = 0; i < 16; ++i) {
        int e = base + i * 256 + tid;
        if (e < E) {
            int s = ei[e];
            int d = ei[E + e];
            int b = d >> SHIFT;
            int p = gbase[b] + lrank[i];
            if (p < CAP)
                staging[(size_t)b * CAP + p] =
                    make_int2(s | ((d & (BNODES - 1)) << 17), __float_as_int(ea[e]));
        }
    }
}

__global__ __launch_bounds__(256) void phase1_kernel(
    const float* __restrict__ x, const float* __restrict__ W1,
    const float* __restrict__ root1, float* __restrict__ h01,
    float* __restrict__ xr,
    const int* __restrict__ ei, const float* __restrict__ ea,
    int* __restrict__ gcur, int2* __restrict__ staging,
    int N, int E, int nbuk, int gemmBlocks)
{
    __shared__ float smem[128 * 48];   // 24576B union: gemm Ws | bin counters
    int tid = threadIdx.x;
    if ((int)blockIdx.x < gemmBlocks)
        gemm_part(smem, blockIdx.x, tid, x, W1, root1, h01, xr, N);
    else
        bin_part(smem, blockIdx.x - gemmBlocks, tid, ei, ea, gcur, staging, E, nbuk);
}

// In-place per-bucket counting sort (node-sorted CSR inside the bucket).
__global__ __launch_bounds__(256) void csr_build_kernel(
    int2* __restrict__ staging, const int* __restrict__ gcur,
    int* __restrict__ roff, int* __restrict__ cnt,
    float* __restrict__ degf, int N)
{
    __shared__ int2 rin[CAP];
    __shared__ int2 rout[CAP];
    __shared__ int hist[BNODES];
    __shared__ int sscan[BNODES];
    __shared__ int wcur[BNODES];
    int tid = threadIdx.x;
    int b = blockIdx.x;
    int m = gcur[b];
    if (m > CAP) m = CAP;
    int2* sp = staging + (size_t)b * CAP;

    if (tid < BNODES) { hist[tid] = 0; wcur[tid] = 0; }
    __syncthreads();
    for (int k = tid; k < m; k += 256) {
        int2 r = sp[k];
        rin[k] = r;
        atomicAdd(&hist[r.x >> 17], 1);
    }
    __syncthreads();
    if (tid < BNODES) sscan[tid] = hist[tid];
    __syncthreads();
    for (int off = 1; off < BNODES; off <<= 1) {
        int t = (tid < BNODES && tid >= off) ? sscan[tid - off] : 0;
        __syncthreads();
        if (tid < BNODES) sscan[tid] += t;
        __syncthreads();
    }
    for (int k = tid; k < m; k += 256) {
        int2 r = rin[k];
        int dl = r.x >> 17;
        int pos = (sscan[dl] - hist[dl]) + atomicAdd(&wcur[dl], 1);
        rout[pos] = make_int2(r.x & 0x1FFFF, r.y);
    }
    __syncthreads();
    for (int k = tid; k < m; k += 256) sp[k] = rout[k];
    if (tid < BNODES) {
        int n = b * BNODES + tid;
        if (n < N) {
            roff[n] = b * CAP + (sscan[tid] - hist[tid]);
            cnt[n]  = hist[tid];
            degf[n] = (float)hist[tid];
        }
    }
}

// Layer-1 gather: 16 lanes per node, lane c owns channel c.
__global__ __launch_bounds__(256) void gather1_kernel(
    const int2* __restrict__ staging, const int* __restrict__ roff,
    const int* __restrict__ cnt, const float* __restrict__ h01,
    float* __restrict__ agg1, int N)
{
    int t = blockIdx.x * 256 + threadIdx.x;
    int n = t >> 4;
    int c = t & 15;
    if (n >= N) return;
    int start = roff[n];
    int m = cnt[n];
    float acc = 0.f;
#pragma unroll 2
    for (int k = 0; k < m; ++k) {
        int2 r = staging[(size_t)start + k];
        int s = r.x;
        float w = __int_as_float(r.y);
        float a = h01[(size_t)s * 32 + c];
        float bb = h01[(size_t)s * 32 + 16 + c];
        acc += a + w * (bb - a);
    }
    agg1[(size_t)n * 16 + c] = acc;
}

// h = elu(agg1/max(deg,1) + xr + b1), in place over xr; hrb = h@root2 + b2
__global__ __launch_bounds__(256) void finalize1_kernel(
    const float* __restrict__ agg1, const float* __restrict__ degf,
    float* __restrict__ xrh, const float* __restrict__ b1,
    const float* __restrict__ root2, const float* __restrict__ b2,
    float* __restrict__ hrb, int N)
{
    __shared__ float r2s[160];
    __shared__ float b1s[16];
    __shared__ float b2s[10];
    int tid = threadIdx.x;
    if (tid < 160) r2s[tid] = root2[tid];
    if (tid < 16)  b1s[tid] = b1[tid];
    if (tid < 10)  b2s[tid] = b2[tid];
    __syncthreads();
    int n = blockIdx.x * 256 + tid;
    if (n >= N) return;

    float invd = 1.0f / fmaxf(degf[n], 1.0f);
    float hv[16];
#pragma unroll
    for (int c = 0; c < 16; ++c) {
        float v = agg1[(size_t)n * 16 + c] * invd + xrh[(size_t)n * 16 + c] + b1s[c];
        hv[c] = v > 0.f ? v : expm1f(v);
    }
    float4* hp = (float4*)(xrh + (size_t)n * 16);
#pragma unroll
    for (int q = 0; q < 4; ++q)
        hp[q] = make_float4(hv[q * 4], hv[q * 4 + 1], hv[q * 4 + 2], hv[q * 4 + 3]);

    float hr[10];
#pragma unroll
    for (int j = 0; j < 10; ++j) hr[j] = b2s[j];
#pragma unroll
    for (int i = 0; i < 16; ++i)
#pragma unroll
        for (int j = 0; j < 10; ++j)
            hr[j] += hv[i] * r2s[i * 10 + j];
    float* hb = hrb + (size_t)n * 10;
#pragma unroll
    for (int j = 0; j < 10; ++j) hb[j] = hr[j];
}

// Layer-2 gather in h-space: p = sum (1-w)h[src], q = sum w*h[src]
__global__ __launch_bounds__(256) void gather2_kernel(
    const int2* __restrict__ staging, const int* __restrict__ roff,
    const int* __restrict__ cnt, const float* __restrict__ h,
    float* __restrict__ pq, int N)
{
    int t = blockIdx.x * 256 + threadIdx.x;
    int n = t >> 4;
    int c = t & 15;
    if (n >= N) return;
    int start = roff[n];
    int m = cnt[n];
    float p = 0.f, q = 0.f;
#pragma unroll 2
    for (int k = 0; k < m; ++k) {
        int2 r = staging[(size_t)start + k];
        float w = __int_as_float(r.y);
        float v = h[(size_t)r.x * 16 + c];
        p += (1.f - w) * v;
        q += w * v;
    }
    pq[(size_t)n * 32 + c]      = p;
    pq[(size_t)n * 32 + 16 + c] = q;
}

// out = (p@W2[0] + q@W2[1])/max(deg,1) + hrb
__global__ __launch_bounds__(256) void finalize2_kernel(
    const float* __restrict__ pq, const float* __restrict__ degf,
    const float* __restrict__ hrb, const float* __restrict__ W2,
    float* __restrict__ out, int N)
{
    __shared__ float w2s[320];
    int tid = threadIdx.x;
    for (int idx = tid; idx < 320; idx += 256) w2s[idx] = W2[idx];
    __syncthreads();
    int n = blockIdx.x * 256 + tid;
    if (n >= N) return;

    float invd = 1.0f / fmaxf(degf[n], 1.0f);
    float pv[16], qv[16];
    const float4* pp = (const float4*)(pq + (size_t)n * 32);
#pragma unroll
    for (int q4 = 0; q4 < 4; ++q4) {
        float4 a = pp[q4];
        pv[q4 * 4] = a.x; pv[q4 * 4 + 1] = a.y; pv[q4 * 4 + 2] = a.z; pv[q4 * 4 + 3] = a.w;
        float4 bq = pp[4 + q4];
        qv[q4 * 4] = bq.x; qv[q4 * 4 + 1] = bq.y; qv[q4 * 4 + 2] = bq.z; qv[q4 * 4 + 3] = bq.w;
    }
    float o[10];
#pragma unroll
    for (int j = 0; j < 10; ++j) o[j] = 0.f;
#pragma unroll
    for (int i = 0; i < 16; ++i)
#pragma unroll
        for (int j = 0; j < 10; ++j)
            o[j] += pv[i] * w2s[i * 10 + j] + qv[i] * w2s[160 + i * 10 + j];
    float* op = out + (size_t)n * 10;
    const float* hb = hrb + (size_t)n * 10;
#pragma unroll
    for (int j = 0; j < 10; ++j) op[j] = o[j] * invd + hb[j];
}

extern "C" void kernel_launch(void* const* d_in, const int* in_sizes, int n_in,
                              void* d_out, int out_size, void* d_ws, size_t ws_size,
                              hipStream_t stream)
{
    const float* x     = (const float*)d_in[0];
    const int*   ei    = (const int*)d_in[1];   // (2,E)
    const float* ea    = (const float*)d_in[2]; // (E,1)
    const float* W1    = (const float*)d_in[3]; // (2,128,16)
    const float* root1 = (const float*)d_in[4]; // (128,16)
    const float* b1    = (const float*)d_in[5]; // (16,)
    const float* W2    = (const float*)d_in[6]; // (2,16,10)
    const float* root2 = (const float*)d_in[7]; // (16,10)
    const float* b2    = (const float*)d_in[8]; // (10,)
    float* out = (float*)d_out;

    int N = in_sizes[0] / 128;
    int E = in_sizes[2];
    int nbuk = (N + BNODES - 1) / BNODES;   // 782

    // workspace layout unchanged from passing r5 (46.0 MB)
    char* ws = (char*)d_ws;
    int2*  staging = (int2*)ws;
    float* buf32 = (float*)(ws + (size_t)nbuk * CAP * 8);
    float* h01   = buf32;
    float* pq    = buf32;
    float* xrh   = buf32 + (size_t)N * 32;
    float* agg1  = xrh  + (size_t)N * 16;
    float* hrb   = agg1 + (size_t)N * 16;
    float* degf  = hrb  + (size_t)N * 10;
    int*   cnt   = (int*)(degf + N);
    int*   roff  = cnt  + N;
    int*   gcur  = roff + N;

    int nb_n = (N + 255) / 256;
    int nb_e16 = (N * 16 + 255) / 256;
    int gemmBlocks = (N + GNODES - 1) / GNODES;        // 782
    int binBlocks  = (E + CHUNK - 1) / CHUNK;          // 391

    hipMemsetAsync(gcur, 0, (size_t)nbuk * sizeof(int), stream);

    phase1_kernel   <<<gemmBlocks + binBlocks, 256, 0, stream>>>(
        x, W1, root1, h01, xrh, ei, ea, gcur, staging, N, E, nbuk, gemmBlocks);
    csr_build_kernel<<<nbuk, 256, 0, stream>>>(staging, gcur, roff, cnt, degf, N);
    gather1_kernel  <<<nb_e16, 256, 0, stream>>>(staging, roff, cnt, h01, agg1, N);
    finalize1_kernel<<<nb_n, 256, 0, stream>>>(agg1, degf, xrh, b1, root2, b2, hrb, N);
    gather2_kernel  <<<nb_e16, 256, 0, stream>>>(staging, roff, cnt, xrh, pq, N);
    finalize2_kernel<<<nb_n, 256, 0, stream>>>(pq, degf, hrb, W2, out, N);
}